// Round 11
// baseline (102.869 us; speedup 1.0000x reference)
//
#include <hip/hip_runtime.h>
#include <hip/hip_fp16.h>

#define N_NODES 50000
#define N_EDGES 800000
#define TOT_E   (N_EDGES + N_NODES)
#define NEG_SLOPE 0.2f
#define MB_SHIFT 8.0f   // fixed softmax shift: valid upper bound for e=as+ad (|e|<~3);
                        // softmax is shift-invariant so result is exact up to fp rounding.

#define SHIFT  6
#define NBUCK  ((N_NODES + 63) >> SHIFT)       // 782 buckets of 64 nodes
#define NBP    1024                             // padded scan width
#define CAP    2048                             // fixed bucket capacity (E[load]=1088, ~29 sigma)
#define CHUNK  4096                             // 208 binscatter blocks
#define EPT    (CHUNK / 256)                    // 16 edges per thread
#define NCHUNK ((TOT_E + CHUNK - 1) / CHUNK)
#define NGEMM1 ((N_NODES + 127) / 128)          // 391 GEMM1 blocks (BM=128)

typedef unsigned short ushort_t;

// ---------- edge fetch (handles int32 or int64 edge_index; self-loops appended) ----------
__device__ __forceinline__ void get_edge(const void* edges, int flag64, long long i,
                                         int& src, int& dst) {
    if (i < N_EDGES) {
        if (flag64) {
            const long long* e = (const long long*)edges;
            src = (int)e[i];
            dst = (int)e[N_EDGES + i];
        } else {
            const int* e = (const int*)edges;
            src = e[i];
            dst = e[(long long)N_EDGES + i];
        }
    } else {
        src = dst = (int)(i - N_EDGES);
    }
}

// per-block edge-dtype detection: wave 0 checks first 64 int64 slots, one ballot.
__device__ __forceinline__ int detect64(const void* edges, int tid, int* sfl) {
    if (tid < 64) {
        long long v = ((const long long*)edges)[tid];
        unsigned long long ok = __ballot(v >= 0 && v < N_NODES);
        if (tid == 0) *sfl = (ok == ~0ull) ? 1 : 0;
    }
    __syncthreads();
    return *sfl;
}

// ---------- zero the per-bucket cursor (3KB) ----------
__global__ __launch_bounds__(256) void k_zero(int* __restrict__ gcnt) {
    int i = blockIdx.x * blockDim.x + threadIdx.x;
    if (i < NBUCK) gcnt[i] = 0;
}

// ---------- merged dispatch: binscatter blocks + GEMM1 blocks (fully independent) ----------
// blocks [0, NCHUNK)            : fixed-capacity binscatter (staging, gcnt)
// blocks [NCHUNK, NCHUNK+NGEMM1): layer-1 GEMM (BM=128, 8x4 tile) + att dots
// LDS is a union (30.8KB) so both branches keep 5 blocks/CU; all 599 blocks co-resident.
__global__ __launch_bounds__(256) void k_scatgemm(
        const void* edges, int* gcnt, unsigned int* staging,
        const float* __restrict__ X, const float* __restrict__ W,
        const float* __restrict__ a_src, const float* __restrict__ a_dst,
        __half* __restrict__ H, float* __restrict__ as_, float* __restrict__ ad_) {
    union SM {
        struct { int sc[NBP]; int so[NBP]; int sr[NBUCK]; int gb[NBUCK];
                 unsigned int buf[CHUNK]; int sfl; } s;
        struct { float Xs[32][128]; float Ws[32][64]; } g;
    };
    __shared__ SM sm;
    const int tid = threadIdx.x;

    if (blockIdx.x < NCHUNK) {
        // ----- binscatter branch -----
        const int c0 = blockIdx.x * CHUNK;
        const int nE = min(CHUNK, TOT_E - c0);
        unsigned int pk[EPT];

        for (int s = 0; s < 4; s++) sm.s.sc[tid + s * 256] = 0;
        for (int i = tid; i < NBUCK; i += 256) sm.s.sr[i] = 0;
        const int fl = detect64(edges, tid, &sm.s.sfl);   // includes __syncthreads()
        // phase 1: read edges, pack, count
#pragma unroll
        for (int j = 0; j < EPT; j++) {
            int li = j * 256 + tid;
            pk[j] = 0u;
            if (li < nE) {
                int src, dst;
                get_edge(edges, fl, (long long)(c0 + li), src, dst);
                pk[j] = ((unsigned int)dst << 16) | (unsigned int)src;
                atomicAdd(&sm.s.sc[dst >> SHIFT], 1);
            }
        }
        __syncthreads();
        for (int s = 0; s < 4; s++) { int i = tid + s * 256; sm.s.so[i] = sm.s.sc[i]; }
        __syncthreads();
        // phase 2: inclusive scan
        for (int off = 1; off < NBP; off <<= 1) {
            int t[4];
            for (int s = 0; s < 4; s++) {
                int a = tid + s * 256;
                t[s] = (a >= off) ? sm.s.sc[a - off] : 0;
            }
            __syncthreads();
            for (int s = 0; s < 4; s++) sm.s.sc[tid + s * 256] += t[s];
            __syncthreads();
        }
        // reserve ranges inside each bucket's fixed region
        for (int b = tid; b < NBUCK; b += 256)
            if (sm.s.so[b]) sm.s.gb[b] = b * CAP + atomicAdd(&gcnt[b], sm.s.so[b]);
        __syncthreads();
        // phase 3: group edges by bucket in LDS
#pragma unroll
        for (int j = 0; j < EPT; j++) {
            int li = j * 256 + tid;
            if (li < nE) {
                int b = pk[j] >> (16 + SHIFT);
                int lofs = sm.s.sc[b] - sm.s.so[b];
                int pos = lofs + atomicAdd(&sm.s.sr[b], 1);
                sm.s.buf[pos] = pk[j];
            }
        }
        __syncthreads();
        // phase 4: coalesced runs to global
        for (int p = tid; p < nE; p += 256) {
            unsigned int e = sm.s.buf[p];
            int b = e >> (16 + SHIFT);
            int lofs = sm.s.sc[b] - sm.s.so[b];
            staging[sm.s.gb[b] + (p - lofs)] = e;
        }
        return;
    }
    // ----- GEMM1 branch: K=128, N=64, BM=128, BK=32, 8x4 register tile -----
    constexpr int K = 128, N = 64, BM = 128, BK = 32;
    constexpr int TCOLS = N / 4;                 // 16
    constexpr int KPT = (BM * BK) / 256;         // 16
    const int bid  = blockIdx.x - NCHUNK;
    const int tcol = tid % TCOLS;
    const int trow = tid / TCOLS;
    const int node0 = bid * BM;
    const int r0 = trow * 8;
    const int c0 = tcol * 4;
    float acc[8][4] = {};

    const int sm_ = tid % BM;
    const int skb = (tid / BM) * KPT;
    const int srow = (node0 + sm_ < N_NODES) ? (node0 + sm_) : (N_NODES - 1);

    for (int k0 = 0; k0 < K; k0 += BK) {
        const float* xp = X + (long long)srow * K + k0 + skb;
#pragma unroll
        for (int j = 0; j < KPT; j += 4) {
            float4 v = *(const float4*)(xp + j);
            sm.g.Xs[skb + j + 0][sm_] = v.x;
            sm.g.Xs[skb + j + 1][sm_] = v.y;
            sm.g.Xs[skb + j + 2][sm_] = v.z;
            sm.g.Xs[skb + j + 3][sm_] = v.w;
        }
#pragma unroll
        for (int i = tid; i < BK * N / 4; i += 256)
            ((float4*)sm.g.Ws)[i] = ((const float4*)W)[(k0 * N) / 4 + i];
        __syncthreads();
#pragma unroll 4
        for (int k = 0; k < BK; ++k) {
            float4 xa = *(const float4*)&sm.g.Xs[k][r0];
            float4 xb = *(const float4*)&sm.g.Xs[k][r0 + 4];
            float4 wb = *(const float4*)&sm.g.Ws[k][c0];
            float xr[8] = {xa.x, xa.y, xa.z, xa.w, xb.x, xb.y, xb.z, xb.w};
            float wc[4] = {wb.x, wb.y, wb.z, wb.w};
#pragma unroll
            for (int i = 0; i < 8; ++i)
#pragma unroll
                for (int j = 0; j < 4; ++j)
                    acc[i][j] += xr[i] * wc[j];
        }
        __syncthreads();
    }

    const float4 asv = *(const float4*)(a_src + c0);
    const float4 adv = *(const float4*)(a_dst + c0);
    const int rbase = node0 + r0;
    float vsr[8], vdr[8];
#pragma unroll
    for (int i = 0; i < 8; ++i) {
        float vs = acc[i][0] * asv.x + acc[i][1] * asv.y + acc[i][2] * asv.z + acc[i][3] * asv.w;
        float vd = acc[i][0] * adv.x + acc[i][1] * adv.y + acc[i][2] * adv.z + acc[i][3] * adv.w;
#pragma unroll
        for (int off = 1; off < TCOLS; off <<= 1) {
            vs += __shfl_xor(vs, off, 64);
            vd += __shfl_xor(vd, off, 64);
        }
        vsr[i] = vs; vdr[i] = vd;
        if (rbase + i < N_NODES) {
            __half2 q0 = __floats2half2_rn(acc[i][0], acc[i][1]);
            __half2 q1 = __floats2half2_rn(acc[i][2], acc[i][3]);
            uint2 raw;
            raw.x = *(unsigned int*)&q0;
            raw.y = *(unsigned int*)&q1;
            *(uint2*)(H + (long long)(rbase + i) * N + c0) = raw;
        }
    }
    if (tcol == 0) {
#pragma unroll
        for (int i = 0; i < 8; ++i) {
            if (rbase + i < N_NODES) {
                as_[rbase + i] = vsr[i];
                ad_[rbase + i] = vdr[i];
            }
        }
    }
}

// ---------- k_node1: per-bucket block = in-LDS bucketsort + layer-1 aggregation
//            + fused layer-2 GEMM. One block per bucket (64 nodes); 4 waves x 8
//            rounds of the proven 2-nodes-per-wave loop; edge lists read from LDS.
//            Writes ushort srt/offs/degs to global for k_node2. ----------
__global__ __launch_bounds__(256) void k_node1(
        const unsigned int* __restrict__ staging, const int* __restrict__ gcnt,
        int* __restrict__ offs, int* __restrict__ degs, ushort_t* __restrict__ gsrt,
        const float* __restrict__ as_, const float* __restrict__ ad_,
        const __half* __restrict__ H, const float* __restrict__ bias,
        const float* __restrict__ W2, const float* __restrict__ a_src2,
        const float* __restrict__ a_dst2,
        __half* __restrict__ g2, float* __restrict__ as2, float* __restrict__ ad2) {
    constexpr int C = 64, G = 8, NR = 4;
    __shared__ ushort_t lsrt[CAP];          // 4KB: node-grouped src ids (16-bit)
    __shared__ int cnt[64], lbase[64], cur[64];
    __shared__ float hrowS[4][2][64];       // per-wave h2 rows
    __shared__ float W2T[32][68];           // transposed W2, pad->16B-aligned rows
    const int tid = threadIdx.x;
    const int b = blockIdx.x;
    const int node0 = b << SHIFT;
    const int nn = min(64, N_NODES - node0);

    // W2T preload: W2T[o][ch] = W2[ch*32+o]
    for (int i = tid; i < 2048; i += 256) W2T[i & 31][i >> 5] = W2[i];
    if (tid < 64) cnt[tid] = 0;
    __syncthreads();
    const int nE = gcnt[b];
    const int gbeg = b * CAP;
    for (int i = tid; i < nE; i += 256)
        atomicAdd(&cnt[(staging[gbeg + i] >> 16) - node0], 1);
    __syncthreads();
    if (tid < 64) {
        int v = cnt[tid];
        int incl = v;
#pragma unroll
        for (int off = 1; off < 64; off <<= 1) {
            int t = __shfl_up(incl, off, 64);
            if (tid >= off) incl += t;
        }
        lbase[tid] = incl - v;
        cur[tid] = 0;
        if (tid < nn) {
            offs[node0 + tid] = gbeg + incl - v;
            degs[node0 + tid] = v;
        }
    }
    __syncthreads();
    for (int i = tid; i < nE; i += 256) {
        unsigned int e = staging[gbeg + i];
        int dl = (int)(e >> 16) - node0;
        int pos = lbase[dl] + atomicAdd(&cur[dl], 1);
        ushort_t us = (ushort_t)(e & 0xFFFFu);
        lsrt[pos] = us;
        gsrt[gbeg + pos] = us;
    }
    __syncthreads();

    // ---- aggregation: wave w, round r -> local nodes (w*8+r)*2 + {0,1} ----
    const int w    = tid >> 6;
    const int lane = tid & 63;
    const int ln   = lane & 31;
    const int hf   = lane >> 5;
    const int g  = ln / G;
    const int cl = ln % G;

    for (int r = 0; r < 8; r++) {
        const int dl = (w * 8 + r) * 2 + hf;
        const int node = node0 + dl;
        const bool nv = dl < nn;
        const int lbeg = lbase[dl];
        const int deg = nv ? cnt[dl] : 0;
        const int mdeg = max(deg, __shfl_xor(deg, 32, 64));
        const float adn = nv ? ad_[node] : 0.f;
        float acc[8] = {};
        float ssum = 0.f;

        for (int base_i = 0; base_i < mdeg; base_i += 32) {
            const int nb  = min(32, deg - base_i);
            const int mnb = min(32, mdeg - base_i);
            // phase A
            int s = 0;
            float p = 0.f;
            if (ln < nb) {
                s = lsrt[lbeg + base_i + ln];
                float e = as_[s] + adn;
                e = (e > 0.f) ? e : NEG_SLOPE * e;
                p = __expf(e - MB_SHIFT);
            }
            ssum += p;
            // phase B
            int j = 0;
            for (; j + NR < mnb; j += 2 * NR) {
                const int i0 = j + g, i1 = j + NR + g;
                const int   s0 = __shfl(s, i0, 32);
                const int   s1 = __shfl(s, i1, 32);
                const float p0 = __shfl(p, i0, 32);
                const float p1 = __shfl(p, i1, 32);
                const uint4 ra = *(const uint4*)(H + (long long)s0 * C + cl * 8);
                const uint4 rb = *(const uint4*)(H + (long long)s1 * C + cl * 8);
                float2 f;
                f = __half22float2(*(const __half2*)&ra.x); acc[0] += p0 * f.x; acc[1] += p0 * f.y;
                f = __half22float2(*(const __half2*)&ra.y); acc[2] += p0 * f.x; acc[3] += p0 * f.y;
                f = __half22float2(*(const __half2*)&ra.z); acc[4] += p0 * f.x; acc[5] += p0 * f.y;
                f = __half22float2(*(const __half2*)&ra.w); acc[6] += p0 * f.x; acc[7] += p0 * f.y;
                f = __half22float2(*(const __half2*)&rb.x); acc[0] += p1 * f.x; acc[1] += p1 * f.y;
                f = __half22float2(*(const __half2*)&rb.y); acc[2] += p1 * f.x; acc[3] += p1 * f.y;
                f = __half22float2(*(const __half2*)&rb.z); acc[4] += p1 * f.x; acc[5] += p1 * f.y;
                f = __half22float2(*(const __half2*)&rb.w); acc[6] += p1 * f.x; acc[7] += p1 * f.y;
            }
            if (j < mnb) {
                const int i0 = j + g;
                const int   s0 = __shfl(s, i0, 32);
                const float p0 = __shfl(p, i0, 32);
                const uint4 ra = *(const uint4*)(H + (long long)s0 * C + cl * 8);
                float2 f;
                f = __half22float2(*(const __half2*)&ra.x); acc[0] += p0 * f.x; acc[1] += p0 * f.y;
                f = __half22float2(*(const __half2*)&ra.y); acc[2] += p0 * f.x; acc[3] += p0 * f.y;
                f = __half22float2(*(const __half2*)&ra.z); acc[4] += p0 * f.x; acc[5] += p0 * f.y;
                f = __half22float2(*(const __half2*)&ra.w); acc[6] += p0 * f.x; acc[7] += p0 * f.y;
            }
        }
#pragma unroll
        for (int off = 1; off < 32; off <<= 1)
            ssum += __shfl_xor(ssum, off, 64);
        const float inv = 1.f / (ssum + 1e-30f);

        // fold-reduce: 2 steps, lane ends owning channels ch, ch+1
        const int b0 = (ln >> 3) & 1, b1 = (ln >> 4) & 1;
        float s0 = b0 ? acc[0] : acc[4];
        float s1 = b0 ? acc[1] : acc[5];
        float s2 = b0 ? acc[2] : acc[6];
        float s3 = b0 ? acc[3] : acc[7];
        float r0 = __shfl_xor(s0, 8, 64);
        float r1 = __shfl_xor(s1, 8, 64);
        float r2 = __shfl_xor(s2, 8, 64);
        float r3 = __shfl_xor(s3, 8, 64);
        float a0 = (b0 ? acc[4] : acc[0]) + r0;
        float a1 = (b0 ? acc[5] : acc[1]) + r1;
        float a2 = (b0 ? acc[6] : acc[2]) + r2;
        float a3 = (b0 ? acc[7] : acc[3]) + r3;
        float t0 = b1 ? a0 : a2;
        float t1 = b1 ? a1 : a3;
        float q0 = __shfl_xor(t0, 16, 64);
        float q1 = __shfl_xor(t1, 16, 64);
        float c0v = (b1 ? a2 : a0) + q0;
        float c1v = (b1 ? a3 : a1) + q1;
        const int ch = cl * 8 + b0 * 4 + b1 * 2;

        float v0 = c0v * inv + bias[ch];
        float v1 = c1v * inv + bias[ch + 1];
        v0 = (v0 > 0.f) ? v0 : expm1f(v0);
        v1 = (v1 > 0.f) ? v1 : expm1f(v1);

        // fused layer-2 GEMM (W2T in LDS; hrow write->read same wave, in-order DS)
        float2 hv2 = {v0, v1};
        *(float2*)&hrowS[w][hf][ch] = hv2;
        float y = 0.f;
#pragma unroll
        for (int cc = 0; cc < 64; cc += 4) {
            float4 hv = *(const float4*)&hrowS[w][hf][cc];
            float4 wv = *(const float4*)&W2T[ln][cc];
            y += hv.x * wv.x + hv.y * wv.y + hv.z * wv.z + hv.w * wv.w;
        }
        float ts = y * a_src2[ln];
        float td = y * a_dst2[ln];
#pragma unroll
        for (int off = 1; off < 32; off <<= 1) {
            ts += __shfl_xor(ts, off, 64);
            td += __shfl_xor(td, off, 64);
        }
        if (nv) {
            g2[(long long)node * 32 + ln] = __float2half_rn(y);
            if (ln == 0) { as2[node] = ts; ad2[node] = td; }
        }
    }
}

// ---------- layer-2 node pass: TWO NODES PER WAVE (C=32, ushort srt) ----------
template<int C, bool ELU>
__global__ __launch_bounds__(256) void k_node(
        const int* __restrict__ offs, const int* __restrict__ degs,
        const ushort_t* __restrict__ srt,
        const float* __restrict__ as_, const float* __restrict__ ad_,
        const __half* __restrict__ H, const float* __restrict__ bias,
        float* __restrict__ out) {
    constexpr int G  = C / 8;     // 4 for C=32
    constexpr int NR = 32 / G;    // 8
    const int wid = (int)(((long long)blockIdx.x * blockDim.x + threadIdx.x) >> 6);
    if (wid * 2 >= N_NODES) return;
    const int lane = threadIdx.x & 63;
    const int ln   = lane & 31;
    const int node = wid * 2 + (lane >> 5);
    const bool nv = node < N_NODES;
    const int beg = nv ? offs[node] : 0;
    const int deg = nv ? degs[node] : 0;
    const int mdeg = max(deg, __shfl_xor(deg, 32, 64));
    const float adn = nv ? ad_[node] : 0.f;
    const int g  = ln / G;
    const int cl = ln % G;
    float acc[8] = {};
    float ssum = 0.f;

    for (int base = 0; base < mdeg; base += 32) {
        const int nb  = min(32, deg - base);
        const int mnb = min(32, mdeg - base);
        int s = 0;
        float p = 0.f;
        if (ln < nb) {
            s = srt[beg + base + ln];
            float e = as_[s] + adn;
            e = (e > 0.f) ? e : NEG_SLOPE * e;
            p = __expf(e - MB_SHIFT);
        }
        ssum += p;
        int j = 0;
        for (; j + NR < mnb; j += 2 * NR) {
            const int i0 = j + g, i1 = j + NR + g;
            const int   s0 = __shfl(s, i0, 32);
            const int   s1 = __shfl(s, i1, 32);
            const float p0 = __shfl(p, i0, 32);
            const float p1 = __shfl(p, i1, 32);
            const uint4 ra = *(const uint4*)(H + (long long)s0 * C + cl * 8);
            const uint4 rb = *(const uint4*)(H + (long long)s1 * C + cl * 8);
            float2 f;
            f = __half22float2(*(const __half2*)&ra.x); acc[0] += p0 * f.x; acc[1] += p0 * f.y;
            f = __half22float2(*(const __half2*)&ra.y); acc[2] += p0 * f.x; acc[3] += p0 * f.y;
            f = __half22float2(*(const __half2*)&ra.z); acc[4] += p0 * f.x; acc[5] += p0 * f.y;
            f = __half22float2(*(const __half2*)&ra.w); acc[6] += p0 * f.x; acc[7] += p0 * f.y;
            f = __half22float2(*(const __half2*)&rb.x); acc[0] += p1 * f.x; acc[1] += p1 * f.y;
            f = __half22float2(*(const __half2*)&rb.y); acc[2] += p1 * f.x; acc[3] += p1 * f.y;
            f = __half22float2(*(const __half2*)&rb.z); acc[4] += p1 * f.x; acc[5] += p1 * f.y;
            f = __half22float2(*(const __half2*)&rb.w); acc[6] += p1 * f.x; acc[7] += p1 * f.y;
        }
        if (j < mnb) {
            const int i0 = j + g;
            const int   s0 = __shfl(s, i0, 32);
            const float p0 = __shfl(p, i0, 32);
            const uint4 ra = *(const uint4*)(H + (long long)s0 * C + cl * 8);
            float2 f;
            f = __half22float2(*(const __half2*)&ra.x); acc[0] += p0 * f.x; acc[1] += p0 * f.y;
            f = __half22float2(*(const __half2*)&ra.y); acc[2] += p0 * f.x; acc[3] += p0 * f.y;
            f = __half22float2(*(const __half2*)&ra.z); acc[4] += p0 * f.x; acc[5] += p0 * f.y;
            f = __half22float2(*(const __half2*)&ra.w); acc[6] += p0 * f.x; acc[7] += p0 * f.y;
        }
    }
#pragma unroll
    for (int off = 1; off < 32; off <<= 1)
        ssum += __shfl_xor(ssum, off, 64);
    const float inv = 1.f / (ssum + 1e-30f);

    // C=32: 3 fold steps; lane owns 1 channel.
    const int b0 = (ln >> 2) & 1, b1 = (ln >> 3) & 1, b2 = (ln >> 4) & 1;
    float s0 = b0 ? acc[0] : acc[4];
    float s1 = b0 ? acc[1] : acc[5];
    float s2 = b0 ? acc[2] : acc[6];
    float s3 = b0 ? acc[3] : acc[7];
    float r0 = __shfl_xor(s0, 4, 64);
    float r1 = __shfl_xor(s1, 4, 64);
    float r2 = __shfl_xor(s2, 4, 64);
    float r3 = __shfl_xor(s3, 4, 64);
    float a0 = (b0 ? acc[4] : acc[0]) + r0;
    float a1 = (b0 ? acc[5] : acc[1]) + r1;
    float a2 = (b0 ? acc[6] : acc[2]) + r2;
    float a3 = (b0 ? acc[7] : acc[3]) + r3;
    float t0 = b1 ? a0 : a2;
    float t1 = b1 ? a1 : a3;
    float q0 = __shfl_xor(t0, 8, 64);
    float q1 = __shfl_xor(t1, 8, 64);
    float c0 = (b1 ? a2 : a0) + q0;
    float c1 = (b1 ? a3 : a1) + q1;
    float u = b2 ? c0 : c1;
    float ww = __shfl_xor(u, 16, 64);
    float v0 = (b2 ? c1 : c0) + ww;
    const int ch = cl * 8 + b0 * 4 + b1 * 2 + b2;
    if (nv) {
        float v = v0 * inv + bias[ch];
        if (ELU) v = (v > 0.f) ? v : expm1f(v);
        out[(long long)node * C + ch] = v;
    }
}

extern "C" void kernel_launch(void* const* d_in, const int* in_sizes, int n_in,
                              void* d_out, int out_size, void* d_ws, size_t ws_size,
                              hipStream_t stream) {
    const float* x      = (const float*)d_in[0];
    const void*  edges  = d_in[1];
    const float* W1     = (const float*)d_in[2];
    const float* a_src1 = (const float*)d_in[3];
    const float* a_dst1 = (const float*)d_in[4];
    const float* b1     = (const float*)d_in[5];
    const float* W2     = (const float*)d_in[6];
    const float* a_src2 = (const float*)d_in[7];
    const float* a_dst2 = (const float*)d_in[8];
    const float* b2     = (const float*)d_in[9];

    char* ws = (char*)d_ws;
    size_t off = 0;
    auto alloc = [&](size_t bytes) { char* p = ws + off; off += (bytes + 255) & ~size_t(255); return p; };
    __half*       h1      = (__half*)      alloc((size_t)N_NODES * 64 * 2);  // fp16 H, layer 1
    __half*       g2      = (__half*)      alloc((size_t)N_NODES * 32 * 2);  // fp16 h, layer 2
    float*        as1     = (float*)       alloc((size_t)N_NODES * 4);
    float*        ad1     = (float*)       alloc((size_t)N_NODES * 4);
    float*        as2     = (float*)       alloc((size_t)N_NODES * 4);
    float*        ad2     = (float*)       alloc((size_t)N_NODES * 4);
    int*          gcnt    = (int*)         alloc((size_t)NBUCK * 4);
    int*          offs    = (int*)         alloc((size_t)N_NODES * 4);
    int*          degs    = (int*)         alloc((size_t)N_NODES * 4);
    unsigned int* staging = (unsigned int*)alloc((size_t)NBUCK * CAP * 4);   // 6.4MB
    ushort_t*     gsrt    = (ushort_t*)    alloc((size_t)NBUCK * CAP * 2);   // 3.2MB
    float*        out     = (float*)d_out;

    const int NODE_BLOCKS = (((N_NODES + 1) / 2) * 64 + 255) / 256;  // 2 nodes/wave

    // 1) zero bucket cursors
    k_zero<<<(NBUCK + 255) / 256, 256, 0, stream>>>(gcnt);
    // 2) binscatter || layer-1 GEMM (independent; union'd LDS)
    k_scatgemm<<<NCHUNK + NGEMM1, 256, 0, stream>>>(
        edges, gcnt, staging, x, W1, a_src1, a_dst1, h1, as1, ad1);
    // 3) per-bucket: in-LDS sort + layer-1 aggregation + fused layer-2 GEMM
    k_node1<<<NBUCK, 256, 0, stream>>>(
        staging, gcnt, offs, degs, gsrt, as1, ad1, h1, b1, W2, a_src2, a_dst2,
        g2, as2, ad2);
    // 4) layer-2 aggregation -> final output
    k_node<32, false><<<NODE_BLOCKS, 256, 0, stream>>>(
        offs, degs, gsrt, as2, ad2, g2, b2, out);
}

// Round 12
// 85.130 us; speedup vs baseline: 1.2084x; 1.2084x over previous
//
#include <hip/hip_runtime.h>
#include <hip/hip_fp16.h>

#define N_NODES 50000
#define N_EDGES 800000
#define TOT_E   (N_EDGES + N_NODES)
#define NEG_SLOPE 0.2f
#define MB_SHIFT 8.0f   // fixed softmax shift: valid upper bound for e=as+ad (|e|<~3);
                        // softmax is shift-invariant so result is exact up to fp rounding.

#define SHIFT  6
#define NBUCK  ((N_NODES + 63) >> SHIFT)       // 782 buckets of 64 nodes
#define NBP    1024                             // padded scan width
#define CAP    2048                             // fixed bucket capacity (E[load]=1088, ~29 sigma)
#define CHUNK  4096                             // 208 binscatter blocks
#define EPT    (CHUNK / 256)                    // 16 edges per thread
#define NCHUNK ((TOT_E + CHUNK - 1) / CHUNK)
#define NGEMM1 ((N_NODES + 127) / 128)          // 391 GEMM1 blocks (BM=128)

typedef unsigned short ushort_t;

// ---------- edge fetch (handles int32 or int64 edge_index; self-loops appended) ----------
__device__ __forceinline__ void get_edge(const void* edges, int flag64, long long i,
                                         int& src, int& dst) {
    if (i < N_EDGES) {
        if (flag64) {
            const long long* e = (const long long*)edges;
            src = (int)e[i];
            dst = (int)e[N_EDGES + i];
        } else {
            const int* e = (const int*)edges;
            src = e[i];
            dst = e[(long long)N_EDGES + i];
        }
    } else {
        src = dst = (int)(i - N_EDGES);
    }
}

// per-block edge-dtype detection: wave 0 checks first 64 int64 slots, one ballot.
__device__ __forceinline__ int detect64(const void* edges, int tid, int* sfl) {
    if (tid < 64) {
        long long v = ((const long long*)edges)[tid];
        unsigned long long ok = __ballot(v >= 0 && v < N_NODES);
        if (tid == 0) *sfl = (ok == ~0ull) ? 1 : 0;
    }
    __syncthreads();
    return *sfl;
}

// ---------- zero the per-bucket cursor (3KB) ----------
__global__ __launch_bounds__(256) void k_zero(int* __restrict__ gcnt) {
    int i = blockIdx.x * blockDim.x + threadIdx.x;
    if (i < NBUCK) gcnt[i] = 0;
}

// ---------- merged dispatch: binscatter blocks + GEMM1 blocks (fully independent) ----------
// blocks [0, NCHUNK)            : fixed-capacity binscatter (staging, gcnt)
// blocks [NCHUNK, NCHUNK+NGEMM1): layer-1 GEMM (BM=128, 8x4 tile) + att dots
// LDS is a union (30.8KB) so both branches keep 5 blocks/CU; all 599 blocks co-resident.
__global__ __launch_bounds__(256) void k_scatgemm(
        const void* edges, int* gcnt, unsigned int* staging,
        const float* __restrict__ X, const float* __restrict__ W,
        const float* __restrict__ a_src, const float* __restrict__ a_dst,
        __half* __restrict__ H, float* __restrict__ as_, float* __restrict__ ad_) {
    union SM {
        struct { int sc[NBP]; int so[NBP]; int sr[NBUCK]; int gb[NBUCK];
                 unsigned int buf[CHUNK]; int sfl; } s;
        struct { float Xs[32][128]; float Ws[32][64]; } g;
    };
    __shared__ SM sm;
    const int tid = threadIdx.x;

    if (blockIdx.x < NCHUNK) {
        // ----- binscatter branch -----
        const int c0 = blockIdx.x * CHUNK;
        const int nE = min(CHUNK, TOT_E - c0);
        unsigned int pk[EPT];

        for (int s = 0; s < 4; s++) sm.s.sc[tid + s * 256] = 0;
        for (int i = tid; i < NBUCK; i += 256) sm.s.sr[i] = 0;
        const int fl = detect64(edges, tid, &sm.s.sfl);   // includes __syncthreads()
        // phase 1: read edges, pack, count
#pragma unroll
        for (int j = 0; j < EPT; j++) {
            int li = j * 256 + tid;
            pk[j] = 0u;
            if (li < nE) {
                int src, dst;
                get_edge(edges, fl, (long long)(c0 + li), src, dst);
                pk[j] = ((unsigned int)dst << 16) | (unsigned int)src;
                atomicAdd(&sm.s.sc[dst >> SHIFT], 1);
            }
        }
        __syncthreads();
        for (int s = 0; s < 4; s++) { int i = tid + s * 256; sm.s.so[i] = sm.s.sc[i]; }
        __syncthreads();
        // phase 2: inclusive scan
        for (int off = 1; off < NBP; off <<= 1) {
            int t[4];
            for (int s = 0; s < 4; s++) {
                int a = tid + s * 256;
                t[s] = (a >= off) ? sm.s.sc[a - off] : 0;
            }
            __syncthreads();
            for (int s = 0; s < 4; s++) sm.s.sc[tid + s * 256] += t[s];
            __syncthreads();
        }
        // reserve ranges inside each bucket's fixed region
        for (int b = tid; b < NBUCK; b += 256)
            if (sm.s.so[b]) sm.s.gb[b] = b * CAP + atomicAdd(&gcnt[b], sm.s.so[b]);
        __syncthreads();
        // phase 3: group edges by bucket in LDS
#pragma unroll
        for (int j = 0; j < EPT; j++) {
            int li = j * 256 + tid;
            if (li < nE) {
                int b = pk[j] >> (16 + SHIFT);
                int lofs = sm.s.sc[b] - sm.s.so[b];
                int pos = lofs + atomicAdd(&sm.s.sr[b], 1);
                sm.s.buf[pos] = pk[j];
            }
        }
        __syncthreads();
        // phase 4: coalesced runs to global
        for (int p = tid; p < nE; p += 256) {
            unsigned int e = sm.s.buf[p];
            int b = e >> (16 + SHIFT);
            int lofs = sm.s.sc[b] - sm.s.so[b];
            staging[sm.s.gb[b] + (p - lofs)] = e;
        }
        return;
    }
    // ----- GEMM1 branch: K=128, N=64, BM=128, BK=32, 8x4 register tile -----
    constexpr int K = 128, N = 64, BM = 128, BK = 32;
    constexpr int TCOLS = N / 4;                 // 16
    constexpr int KPT = (BM * BK) / 256;         // 16
    const int bid  = blockIdx.x - NCHUNK;
    const int tcol = tid % TCOLS;
    const int trow = tid / TCOLS;
    const int node0 = bid * BM;
    const int r0 = trow * 8;
    const int c0 = tcol * 4;
    float acc[8][4] = {};

    const int sm_ = tid % BM;
    const int skb = (tid / BM) * KPT;
    const int srow = (node0 + sm_ < N_NODES) ? (node0 + sm_) : (N_NODES - 1);

    for (int k0 = 0; k0 < K; k0 += BK) {
        const float* xp = X + (long long)srow * K + k0 + skb;
#pragma unroll
        for (int j = 0; j < KPT; j += 4) {
            float4 v = *(const float4*)(xp + j);
            sm.g.Xs[skb + j + 0][sm_] = v.x;
            sm.g.Xs[skb + j + 1][sm_] = v.y;
            sm.g.Xs[skb + j + 2][sm_] = v.z;
            sm.g.Xs[skb + j + 3][sm_] = v.w;
        }
#pragma unroll
        for (int i = tid; i < BK * N / 4; i += 256)
            ((float4*)sm.g.Ws)[i] = ((const float4*)W)[(k0 * N) / 4 + i];
        __syncthreads();
#pragma unroll 4
        for (int k = 0; k < BK; ++k) {
            float4 xa = *(const float4*)&sm.g.Xs[k][r0];
            float4 xb = *(const float4*)&sm.g.Xs[k][r0 + 4];
            float4 wb = *(const float4*)&sm.g.Ws[k][c0];
            float xr[8] = {xa.x, xa.y, xa.z, xa.w, xb.x, xb.y, xb.z, xb.w};
            float wc[4] = {wb.x, wb.y, wb.z, wb.w};
#pragma unroll
            for (int i = 0; i < 8; ++i)
#pragma unroll
                for (int j = 0; j < 4; ++j)
                    acc[i][j] += xr[i] * wc[j];
        }
        __syncthreads();
    }

    const float4 asv = *(const float4*)(a_src + c0);
    const float4 adv = *(const float4*)(a_dst + c0);
    const int rbase = node0 + r0;
    float vsr[8], vdr[8];
#pragma unroll
    for (int i = 0; i < 8; ++i) {
        float vs = acc[i][0] * asv.x + acc[i][1] * asv.y + acc[i][2] * asv.z + acc[i][3] * asv.w;
        float vd = acc[i][0] * adv.x + acc[i][1] * adv.y + acc[i][2] * adv.z + acc[i][3] * adv.w;
#pragma unroll
        for (int off = 1; off < TCOLS; off <<= 1) {
            vs += __shfl_xor(vs, off, 64);
            vd += __shfl_xor(vd, off, 64);
        }
        vsr[i] = vs; vdr[i] = vd;
        if (rbase + i < N_NODES) {
            __half2 q0 = __floats2half2_rn(acc[i][0], acc[i][1]);
            __half2 q1 = __floats2half2_rn(acc[i][2], acc[i][3]);
            uint2 raw;
            raw.x = *(unsigned int*)&q0;
            raw.y = *(unsigned int*)&q1;
            *(uint2*)(H + (long long)(rbase + i) * N + c0) = raw;
        }
    }
    if (tcol == 0) {
#pragma unroll
        for (int i = 0; i < 8; ++i) {
            if (rbase + i < N_NODES) {
                as_[rbase + i] = vsr[i];
                ad_[rbase + i] = vdr[i];
            }
        }
    }
}

// ---------- per-bucket sort: staging region -> node-grouped ushort srt + offs/degs ----------
__global__ __launch_bounds__(256) void k_bsort(
        const unsigned int* __restrict__ staging, const int* __restrict__ gcnt,
        int* __restrict__ offs, int* __restrict__ degs, ushort_t* __restrict__ gsrt) {
    __shared__ int cnt[64];
    __shared__ int base[64];
    __shared__ int cur[64];
    const int b = blockIdx.x;
    const int node0 = b << SHIFT;
    const int nn = min(64, N_NODES - node0);
    const int tid = threadIdx.x;
    if (tid < 64) cnt[tid] = 0;
    __syncthreads();
    const int gbeg = b * CAP;
    const int nE = gcnt[b];
    for (int i = tid; i < nE; i += 256)
        atomicAdd(&cnt[(staging[gbeg + i] >> 16) - node0], 1);
    __syncthreads();
    if (tid < 64) {
        int v = cnt[tid];
        int incl = v;
#pragma unroll
        for (int off = 1; off < 64; off <<= 1) {
            int t = __shfl_up(incl, off, 64);
            if (tid >= off) incl += t;
        }
        base[tid] = gbeg + incl - v;
        cur[tid] = 0;
        if (tid < nn) {
            offs[node0 + tid] = gbeg + incl - v;
            degs[node0 + tid] = v;
        }
    }
    __syncthreads();
    for (int i = tid; i < nE; i += 256) {
        unsigned int e = staging[gbeg + i];
        int dl = (int)(e >> 16) - node0;
        int pos = base[dl] + atomicAdd(&cur[dl], 1);
        gsrt[pos] = (ushort_t)(e & 0xFFFFu);
    }
}

// ---------- layer-1 node pass, TWO NODES PER WAVE, with FUSED layer-2 GEMM ----------
// (round-10 proven form: 6250 independent blocks, ~61% occupancy; r11's per-bucket
//  variant collapsed occupancy to 17% and regressed -- reverted.)
__global__ __launch_bounds__(256) void k_node1(
        const int* __restrict__ offs, const int* __restrict__ degs,
        const ushort_t* __restrict__ srt,
        const float* __restrict__ as_, const float* __restrict__ ad_,
        const __half* __restrict__ H, const float* __restrict__ bias,
        const float* __restrict__ W2, const float* __restrict__ a_src2,
        const float* __restrict__ a_dst2,
        __half* __restrict__ g2, float* __restrict__ as2, float* __restrict__ ad2) {
    constexpr int C = 64, G = 8, NR = 4;   // G lanes/row, NR rows per slot per node
    __shared__ float hrow[4][2][64];       // [wave-in-block][half][channel]
    const int wid = (int)(((long long)blockIdx.x * blockDim.x + threadIdx.x) >> 6);
    if (wid * 2 >= N_NODES) return;
    const int lane = threadIdx.x & 63;
    const int ln   = lane & 31;
    const int node = wid * 2 + (lane >> 5);
    const bool nv = node < N_NODES;
    const int beg = nv ? offs[node] : 0;
    const int deg = nv ? degs[node] : 0;
    const int mdeg = max(deg, __shfl_xor(deg, 32, 64));
    const float adn = nv ? ad_[node] : 0.f;
    const int g  = ln / G;
    const int cl = ln % G;
    float acc[8] = {};
    float ssum = 0.f;

    for (int base = 0; base < mdeg; base += 32) {
        const int nb  = min(32, deg - base);
        const int mnb = min(32, mdeg - base);
        // ---- phase A ----
        int s = 0;
        float p = 0.f;
        if (ln < nb) {
            s = srt[beg + base + ln];
            float e = as_[s] + adn;
            e = (e > 0.f) ? e : NEG_SLOPE * e;
            p = __expf(e - MB_SHIFT);
        }
        ssum += p;
        // ---- phase B ----
        int j = 0;
        for (; j + NR < mnb; j += 2 * NR) {
            const int i0 = j + g, i1 = j + NR + g;
            const int   s0 = __shfl(s, i0, 32);
            const int   s1 = __shfl(s, i1, 32);
            const float p0 = __shfl(p, i0, 32);
            const float p1 = __shfl(p, i1, 32);
            const uint4 ra = *(const uint4*)(H + (long long)s0 * C + cl * 8);
            const uint4 rb = *(const uint4*)(H + (long long)s1 * C + cl * 8);
            float2 f;
            f = __half22float2(*(const __half2*)&ra.x); acc[0] += p0 * f.x; acc[1] += p0 * f.y;
            f = __half22float2(*(const __half2*)&ra.y); acc[2] += p0 * f.x; acc[3] += p0 * f.y;
            f = __half22float2(*(const __half2*)&ra.z); acc[4] += p0 * f.x; acc[5] += p0 * f.y;
            f = __half22float2(*(const __half2*)&ra.w); acc[6] += p0 * f.x; acc[7] += p0 * f.y;
            f = __half22float2(*(const __half2*)&rb.x); acc[0] += p1 * f.x; acc[1] += p1 * f.y;
            f = __half22float2(*(const __half2*)&rb.y); acc[2] += p1 * f.x; acc[3] += p1 * f.y;
            f = __half22float2(*(const __half2*)&rb.z); acc[4] += p1 * f.x; acc[5] += p1 * f.y;
            f = __half22float2(*(const __half2*)&rb.w); acc[6] += p1 * f.x; acc[7] += p1 * f.y;
        }
        if (j < mnb) {
            const int i0 = j + g;
            const int   s0 = __shfl(s, i0, 32);
            const float p0 = __shfl(p, i0, 32);
            const uint4 ra = *(const uint4*)(H + (long long)s0 * C + cl * 8);
            float2 f;
            f = __half22float2(*(const __half2*)&ra.x); acc[0] += p0 * f.x; acc[1] += p0 * f.y;
            f = __half22float2(*(const __half2*)&ra.y); acc[2] += p0 * f.x; acc[3] += p0 * f.y;
            f = __half22float2(*(const __half2*)&ra.z); acc[4] += p0 * f.x; acc[5] += p0 * f.y;
            f = __half22float2(*(const __half2*)&ra.w); acc[6] += p0 * f.x; acc[7] += p0 * f.y;
        }
    }
    // ssum within each half
#pragma unroll
    for (int off = 1; off < 32; off <<= 1)
        ssum += __shfl_xor(ssum, off, 64);
    const float inv = 1.f / (ssum + 1e-30f);

    // fold-reduce: 2 steps, lane ends owning channels ch, ch+1
    const int b0 = (ln >> 3) & 1, b1 = (ln >> 4) & 1;
    float s0 = b0 ? acc[0] : acc[4];
    float s1 = b0 ? acc[1] : acc[5];
    float s2 = b0 ? acc[2] : acc[6];
    float s3 = b0 ? acc[3] : acc[7];
    float r0 = __shfl_xor(s0, 8, 64);
    float r1 = __shfl_xor(s1, 8, 64);
    float r2 = __shfl_xor(s2, 8, 64);
    float r3 = __shfl_xor(s3, 8, 64);
    float a0 = (b0 ? acc[4] : acc[0]) + r0;
    float a1 = (b0 ? acc[5] : acc[1]) + r1;
    float a2 = (b0 ? acc[6] : acc[2]) + r2;
    float a3 = (b0 ? acc[7] : acc[3]) + r3;
    float t0 = b1 ? a0 : a2;
    float t1 = b1 ? a1 : a3;
    float q0 = __shfl_xor(t0, 16, 64);
    float q1 = __shfl_xor(t1, 16, 64);
    float c0v = (b1 ? a2 : a0) + q0;
    float c1v = (b1 ? a3 : a1) + q1;
    const int ch = cl * 8 + b0 * 4 + b1 * 2;

    // bias + ELU -> h2 row values
    float v0 = c0v * inv + bias[ch];
    float v1 = c1v * inv + bias[ch + 1];
    v0 = (v0 > 0.f) ? v0 : expm1f(v0);
    v1 = (v1 > 0.f) ? v1 : expm1f(v1);

    // ---- fused layer-2 GEMM ----
    const int w  = threadIdx.x >> 6;
    const int hf = lane >> 5;
    float2 hv2 = {v0, v1};
    *(float2*)&hrow[w][hf][ch] = hv2;    // intra-wave: ds_write then ds_read, in order

    float y = 0.f;
    const float* wp = W2 + ln;           // W2[ch][ln] = W2[ch*32+ln], coalesced per ch
#pragma unroll
    for (int cc = 0; cc < 64; cc += 4) {
        float4 hv = *(const float4*)&hrow[w][hf][cc];   // broadcast read
        y += hv.x * wp[(cc + 0) * 32] + hv.y * wp[(cc + 1) * 32]
           + hv.z * wp[(cc + 2) * 32] + hv.w * wp[(cc + 3) * 32];
    }
    // attention dots for layer 2
    float ts = y * a_src2[ln];
    float td = y * a_dst2[ln];
#pragma unroll
    for (int off = 1; off < 32; off <<= 1) {
        ts += __shfl_xor(ts, off, 64);
        td += __shfl_xor(td, off, 64);
    }
    if (nv) {
        g2[(long long)node * 32 + ln] = __float2half_rn(y);
        if (ln == 0) { as2[node] = ts; ad2[node] = td; }
    }
}

// ---------- layer-2 node pass: TWO NODES PER WAVE (C=32, ushort srt) ----------
template<int C, bool ELU>
__global__ __launch_bounds__(256) void k_node(
        const int* __restrict__ offs, const int* __restrict__ degs,
        const ushort_t* __restrict__ srt,
        const float* __restrict__ as_, const float* __restrict__ ad_,
        const __half* __restrict__ H, const float* __restrict__ bias,
        float* __restrict__ out) {
    constexpr int G  = C / 8;     // 4 for C=32
    constexpr int NR = 32 / G;    // 8
    const int wid = (int)(((long long)blockIdx.x * blockDim.x + threadIdx.x) >> 6);
    if (wid * 2 >= N_NODES) return;
    const int lane = threadIdx.x & 63;
    const int ln   = lane & 31;
    const int node = wid * 2 + (lane >> 5);
    const bool nv = node < N_NODES;
    const int beg = nv ? offs[node] : 0;
    const int deg = nv ? degs[node] : 0;
    const int mdeg = max(deg, __shfl_xor(deg, 32, 64));
    const float adn = nv ? ad_[node] : 0.f;
    const int g  = ln / G;
    const int cl = ln % G;
    float acc[8] = {};
    float ssum = 0.f;

    for (int base = 0; base < mdeg; base += 32) {
        const int nb  = min(32, deg - base);
        const int mnb = min(32, mdeg - base);
        int s = 0;
        float p = 0.f;
        if (ln < nb) {
            s = srt[beg + base + ln];
            float e = as_[s] + adn;
            e = (e > 0.f) ? e : NEG_SLOPE * e;
            p = __expf(e - MB_SHIFT);
        }
        ssum += p;
        int j = 0;
        for (; j + NR < mnb; j += 2 * NR) {
            const int i0 = j + g, i1 = j + NR + g;
            const int   s0 = __shfl(s, i0, 32);
            const int   s1 = __shfl(s, i1, 32);
            const float p0 = __shfl(p, i0, 32);
            const float p1 = __shfl(p, i1, 32);
            const uint4 ra = *(const uint4*)(H + (long long)s0 * C + cl * 8);
            const uint4 rb = *(const uint4*)(H + (long long)s1 * C + cl * 8);
            float2 f;
            f = __half22float2(*(const __half2*)&ra.x); acc[0] += p0 * f.x; acc[1] += p0 * f.y;
            f = __half22float2(*(const __half2*)&ra.y); acc[2] += p0 * f.x; acc[3] += p0 * f.y;
            f = __half22float2(*(const __half2*)&ra.z); acc[4] += p0 * f.x; acc[5] += p0 * f.y;
            f = __half22float2(*(const __half2*)&ra.w); acc[6] += p0 * f.x; acc[7] += p0 * f.y;
            f = __half22float2(*(const __half2*)&rb.x); acc[0] += p1 * f.x; acc[1] += p1 * f.y;
            f = __half22float2(*(const __half2*)&rb.y); acc[2] += p1 * f.x; acc[3] += p1 * f.y;
            f = __half22float2(*(const __half2*)&rb.z); acc[4] += p1 * f.x; acc[5] += p1 * f.y;
            f = __half22float2(*(const __half2*)&rb.w); acc[6] += p1 * f.x; acc[7] += p1 * f.y;
        }
        if (j < mnb) {
            const int i0 = j + g;
            const int   s0 = __shfl(s, i0, 32);
            const float p0 = __shfl(p, i0, 32);
            const uint4 ra = *(const uint4*)(H + (long long)s0 * C + cl * 8);
            float2 f;
            f = __half22float2(*(const __half2*)&ra.x); acc[0] += p0 * f.x; acc[1] += p0 * f.y;
            f = __half22float2(*(const __half2*)&ra.y); acc[2] += p0 * f.x; acc[3] += p0 * f.y;
            f = __half22float2(*(const __half2*)&ra.z); acc[4] += p0 * f.x; acc[5] += p0 * f.y;
            f = __half22float2(*(const __half2*)&ra.w); acc[6] += p0 * f.x; acc[7] += p0 * f.y;
        }
    }
#pragma unroll
    for (int off = 1; off < 32; off <<= 1)
        ssum += __shfl_xor(ssum, off, 64);
    const float inv = 1.f / (ssum + 1e-30f);

    // C=32: 3 fold steps; lane owns 1 channel.
    const int b0 = (ln >> 2) & 1, b1 = (ln >> 3) & 1, b2 = (ln >> 4) & 1;
    float s0 = b0 ? acc[0] : acc[4];
    float s1 = b0 ? acc[1] : acc[5];
    float s2 = b0 ? acc[2] : acc[6];
    float s3 = b0 ? acc[3] : acc[7];
    float r0 = __shfl_xor(s0, 4, 64);
    float r1 = __shfl_xor(s1, 4, 64);
    float r2 = __shfl_xor(s2, 4, 64);
    float r3 = __shfl_xor(s3, 4, 64);
    float a0 = (b0 ? acc[4] : acc[0]) + r0;
    float a1 = (b0 ? acc[5] : acc[1]) + r1;
    float a2 = (b0 ? acc[6] : acc[2]) + r2;
    float a3 = (b0 ? acc[7] : acc[3]) + r3;
    float t0 = b1 ? a0 : a2;
    float t1 = b1 ? a1 : a3;
    float q0 = __shfl_xor(t0, 8, 64);
    float q1 = __shfl_xor(t1, 8, 64);
    float c0 = (b1 ? a2 : a0) + q0;
    float c1 = (b1 ? a3 : a1) + q1;
    float u = b2 ? c0 : c1;
    float ww = __shfl_xor(u, 16, 64);
    float v0 = (b2 ? c1 : c0) + ww;
    const int ch = cl * 8 + b0 * 4 + b1 * 2 + b2;
    if (nv) {
        float v = v0 * inv + bias[ch];
        if (ELU) v = (v > 0.f) ? v : expm1f(v);
        out[(long long)node * C + ch] = v;
    }
}

extern "C" void kernel_launch(void* const* d_in, const int* in_sizes, int n_in,
                              void* d_out, int out_size, void* d_ws, size_t ws_size,
                              hipStream_t stream) {
    const float* x      = (const float*)d_in[0];
    const void*  edges  = d_in[1];
    const float* W1     = (const float*)d_in[2];
    const float* a_src1 = (const float*)d_in[3];
    const float* a_dst1 = (const float*)d_in[4];
    const float* b1     = (const float*)d_in[5];
    const float* W2     = (const float*)d_in[6];
    const float* a_src2 = (const float*)d_in[7];
    const float* a_dst2 = (const float*)d_in[8];
    const float* b2     = (const float*)d_in[9];

    char* ws = (char*)d_ws;
    size_t off = 0;
    auto alloc = [&](size_t bytes) { char* p = ws + off; off += (bytes + 255) & ~size_t(255); return p; };
    __half*       h1      = (__half*)      alloc((size_t)N_NODES * 64 * 2);  // fp16 H, layer 1
    __half*       g2      = (__half*)      alloc((size_t)N_NODES * 32 * 2);  // fp16 h, layer 2
    float*        as1     = (float*)       alloc((size_t)N_NODES * 4);
    float*        ad1     = (float*)       alloc((size_t)N_NODES * 4);
    float*        as2     = (float*)       alloc((size_t)N_NODES * 4);
    float*        ad2     = (float*)       alloc((size_t)N_NODES * 4);
    int*          gcnt    = (int*)         alloc((size_t)NBUCK * 4);
    int*          offs    = (int*)         alloc((size_t)N_NODES * 4);
    int*          degs    = (int*)         alloc((size_t)N_NODES * 4);
    unsigned int* staging = (unsigned int*)alloc((size_t)NBUCK * CAP * 4);   // 6.4MB
    ushort_t*     gsrt    = (ushort_t*)    alloc((size_t)NBUCK * CAP * 2);   // 3.2MB
    float*        out     = (float*)d_out;

    const int NODE_BLOCKS = (((N_NODES + 1) / 2) * 64 + 255) / 256;  // 2 nodes/wave

    // 1) zero bucket cursors
    k_zero<<<(NBUCK + 255) / 256, 256, 0, stream>>>(gcnt);
    // 2) binscatter || layer-1 GEMM (independent; union'd LDS)
    k_scatgemm<<<NCHUNK + NGEMM1, 256, 0, stream>>>(
        edges, gcnt, staging, x, W1, a_src1, a_dst1, h1, as1, ad1);
    // 3) per-bucket sort -> ushort srt + offs/degs
    k_bsort<<<NBUCK, 256, 0, stream>>>(staging, gcnt, offs, degs, gsrt);
    // 4) layer-1 aggregation + ELU + FUSED layer-2 GEMM + att dots (2 nodes/wave)
    k_node1<<<NODE_BLOCKS, 256, 0, stream>>>(
        offs, degs, gsrt, as1, ad1, h1, b1, W2, a_src2, a_dst2, g2, as2, ad2);
    // 5) layer-2 aggregation -> final output
    k_node<32, false><<<NODE_BLOCKS, 256, 0, stream>>>(
        offs, degs, gsrt, as2, ad2, g2, b2, out);
}

// Round 13
// 84.987 us; speedup vs baseline: 1.2104x; 1.0017x over previous
//
#include <hip/hip_runtime.h>
#include <hip/hip_fp16.h>

#define N_NODES 50000
#define N_EDGES 800000
#define TOT_E   (N_EDGES + N_NODES)
#define NEG_SLOPE 0.2f
#define MB_SHIFT 8.0f   // fixed softmax shift: valid upper bound for e=as+ad (|e|<~3);
                        // softmax is shift-invariant so result is exact up to fp rounding.

#define SHIFT  6
#define NBUCK  ((N_NODES + 63) >> SHIFT)       // 782 buckets of 64 nodes
#define NBP    1024                             // padded scan width
#define CAP    2048                             // fixed bucket capacity (E[load]=1088, ~29 sigma)
#define CHUNK  4096                             // 208 binscatter blocks
#define EPT    (CHUNK / 256)                    // 16 edges per thread
#define NCHUNK ((TOT_E + CHUNK - 1) / CHUNK)
#define NGEMM1 ((N_NODES + 127) / 128)          // 391 GEMM1 blocks (BM=128)

typedef unsigned short ushort_t;

// ---------- v_fma_mix_f32: acc += f16(half of h2) * p, conversion fused into FMA ----------
// Replaces 2x v_cvt_f32_f16 + 2x v_fma_f32 with 2x v_fma_mix_f32 (halves phase-B VALU).
__device__ __forceinline__ void fmix(float& lo, float& hi, unsigned int h2, float p) {
    asm("v_fma_mix_f32 %0, %2, %3, %0 op_sel:[0,0,0] op_sel_hi:[1,0,0]\n\t"
        "v_fma_mix_f32 %1, %2, %3, %1 op_sel:[1,0,0] op_sel_hi:[1,0,0]"
        : "+v"(lo), "+v"(hi) : "v"(h2), "v"(p));
}

// ---------- edge fetch (handles int32 or int64 edge_index; self-loops appended) ----------
__device__ __forceinline__ void get_edge(const void* edges, int flag64, long long i,
                                         int& src, int& dst) {
    if (i < N_EDGES) {
        if (flag64) {
            const long long* e = (const long long*)edges;
            src = (int)e[i];
            dst = (int)e[N_EDGES + i];
        } else {
            const int* e = (const int*)edges;
            src = e[i];
            dst = e[(long long)N_EDGES + i];
        }
    } else {
        src = dst = (int)(i - N_EDGES);
    }
}

// per-block edge-dtype detection: wave 0 checks first 64 int64 slots, one ballot.
__device__ __forceinline__ int detect64(const void* edges, int tid, int* sfl) {
    if (tid < 64) {
        long long v = ((const long long*)edges)[tid];
        unsigned long long ok = __ballot(v >= 0 && v < N_NODES);
        if (tid == 0) *sfl = (ok == ~0ull) ? 1 : 0;
    }
    __syncthreads();
    return *sfl;
}

// ---------- zero the per-bucket cursor (3KB) ----------
__global__ __launch_bounds__(256) void k_zero(int* __restrict__ gcnt) {
    int i = blockIdx.x * blockDim.x + threadIdx.x;
    if (i < NBUCK) gcnt[i] = 0;
}

// ---------- merged dispatch: binscatter blocks + GEMM1 blocks (fully independent) ----------
__global__ __launch_bounds__(256) void k_scatgemm(
        const void* edges, int* gcnt, unsigned int* staging,
        const float* __restrict__ X, const float* __restrict__ W,
        const float* __restrict__ a_src, const float* __restrict__ a_dst,
        __half* __restrict__ H, float* __restrict__ as_, float* __restrict__ ad_) {
    union SM {
        struct { int sc[NBP]; int so[NBP]; int sr[NBUCK]; int gb[NBUCK];
                 unsigned int buf[CHUNK]; int sfl; } s;
        struct { float Xs[32][128]; float Ws[32][64]; } g;
    };
    __shared__ SM sm;
    const int tid = threadIdx.x;

    if (blockIdx.x < NCHUNK) {
        // ----- binscatter branch -----
        const int c0 = blockIdx.x * CHUNK;
        const int nE = min(CHUNK, TOT_E - c0);
        unsigned int pk[EPT];

        for (int s = 0; s < 4; s++) sm.s.sc[tid + s * 256] = 0;
        for (int i = tid; i < NBUCK; i += 256) sm.s.sr[i] = 0;
        const int fl = detect64(edges, tid, &sm.s.sfl);   // includes __syncthreads()
        // phase 1: read edges, pack, count
#pragma unroll
        for (int j = 0; j < EPT; j++) {
            int li = j * 256 + tid;
            pk[j] = 0u;
            if (li < nE) {
                int src, dst;
                get_edge(edges, fl, (long long)(c0 + li), src, dst);
                pk[j] = ((unsigned int)dst << 16) | (unsigned int)src;
                atomicAdd(&sm.s.sc[dst >> SHIFT], 1);
            }
        }
        __syncthreads();
        for (int s = 0; s < 4; s++) { int i = tid + s * 256; sm.s.so[i] = sm.s.sc[i]; }
        __syncthreads();
        // phase 2: inclusive scan
        for (int off = 1; off < NBP; off <<= 1) {
            int t[4];
            for (int s = 0; s < 4; s++) {
                int a = tid + s * 256;
                t[s] = (a >= off) ? sm.s.sc[a - off] : 0;
            }
            __syncthreads();
            for (int s = 0; s < 4; s++) sm.s.sc[tid + s * 256] += t[s];
            __syncthreads();
        }
        // reserve ranges inside each bucket's fixed region
        for (int b = tid; b < NBUCK; b += 256)
            if (sm.s.so[b]) sm.s.gb[b] = b * CAP + atomicAdd(&gcnt[b], sm.s.so[b]);
        __syncthreads();
        // phase 3: group edges by bucket in LDS
#pragma unroll
        for (int j = 0; j < EPT; j++) {
            int li = j * 256 + tid;
            if (li < nE) {
                int b = pk[j] >> (16 + SHIFT);
                int lofs = sm.s.sc[b] - sm.s.so[b];
                int pos = lofs + atomicAdd(&sm.s.sr[b], 1);
                sm.s.buf[pos] = pk[j];
            }
        }
        __syncthreads();
        // phase 4: coalesced runs to global
        for (int p = tid; p < nE; p += 256) {
            unsigned int e = sm.s.buf[p];
            int b = e >> (16 + SHIFT);
            int lofs = sm.s.sc[b] - sm.s.so[b];
            staging[sm.s.gb[b] + (p - lofs)] = e;
        }
        return;
    }
    // ----- GEMM1 branch: K=128, N=64, BM=128, BK=32, 8x4 register tile -----
    constexpr int K = 128, N = 64, BM = 128, BK = 32;
    constexpr int TCOLS = N / 4;                 // 16
    constexpr int KPT = (BM * BK) / 256;         // 16
    const int bid  = blockIdx.x - NCHUNK;
    const int tcol = tid % TCOLS;
    const int trow = tid / TCOLS;
    const int node0 = bid * BM;
    const int r0 = trow * 8;
    const int c0 = tcol * 4;
    float acc[8][4] = {};

    const int sm_ = tid % BM;
    const int skb = (tid / BM) * KPT;
    const int srow = (node0 + sm_ < N_NODES) ? (node0 + sm_) : (N_NODES - 1);

    for (int k0 = 0; k0 < K; k0 += BK) {
        const float* xp = X + (long long)srow * K + k0 + skb;
#pragma unroll
        for (int j = 0; j < KPT; j += 4) {
            float4 v = *(const float4*)(xp + j);
            sm.g.Xs[skb + j + 0][sm_] = v.x;
            sm.g.Xs[skb + j + 1][sm_] = v.y;
            sm.g.Xs[skb + j + 2][sm_] = v.z;
            sm.g.Xs[skb + j + 3][sm_] = v.w;
        }
#pragma unroll
        for (int i = tid; i < BK * N / 4; i += 256)
            ((float4*)sm.g.Ws)[i] = ((const float4*)W)[(k0 * N) / 4 + i];
        __syncthreads();
#pragma unroll 4
        for (int k = 0; k < BK; ++k) {
            float4 xa = *(const float4*)&sm.g.Xs[k][r0];
            float4 xb = *(const float4*)&sm.g.Xs[k][r0 + 4];
            float4 wb = *(const float4*)&sm.g.Ws[k][c0];
            float xr[8] = {xa.x, xa.y, xa.z, xa.w, xb.x, xb.y, xb.z, xb.w};
            float wc[4] = {wb.x, wb.y, wb.z, wb.w};
#pragma unroll
            for (int i = 0; i < 8; ++i)
#pragma unroll
                for (int j = 0; j < 4; ++j)
                    acc[i][j] += xr[i] * wc[j];
        }
        __syncthreads();
    }

    const float4 asv = *(const float4*)(a_src + c0);
    const float4 adv = *(const float4*)(a_dst + c0);
    const int rbase = node0 + r0;
    float vsr[8], vdr[8];
#pragma unroll
    for (int i = 0; i < 8; ++i) {
        float vs = acc[i][0] * asv.x + acc[i][1] * asv.y + acc[i][2] * asv.z + acc[i][3] * asv.w;
        float vd = acc[i][0] * adv.x + acc[i][1] * adv.y + acc[i][2] * adv.z + acc[i][3] * adv.w;
#pragma unroll
        for (int off = 1; off < TCOLS; off <<= 1) {
            vs += __shfl_xor(vs, off, 64);
            vd += __shfl_xor(vd, off, 64);
        }
        vsr[i] = vs; vdr[i] = vd;
        if (rbase + i < N_NODES) {
            __half2 q0 = __floats2half2_rn(acc[i][0], acc[i][1]);
            __half2 q1 = __floats2half2_rn(acc[i][2], acc[i][3]);
            uint2 raw;
            raw.x = *(unsigned int*)&q0;
            raw.y = *(unsigned int*)&q1;
            *(uint2*)(H + (long long)(rbase + i) * N + c0) = raw;
        }
    }
    if (tcol == 0) {
#pragma unroll
        for (int i = 0; i < 8; ++i) {
            if (rbase + i < N_NODES) {
                as_[rbase + i] = vsr[i];
                ad_[rbase + i] = vdr[i];
            }
        }
    }
}

// ---------- per-bucket sort: staging region -> node-grouped ushort srt + offs/degs ----------
__global__ __launch_bounds__(256) void k_bsort(
        const unsigned int* __restrict__ staging, const int* __restrict__ gcnt,
        int* __restrict__ offs, int* __restrict__ degs, ushort_t* __restrict__ gsrt) {
    __shared__ int cnt[64];
    __shared__ int base[64];
    __shared__ int cur[64];
    const int b = blockIdx.x;
    const int node0 = b << SHIFT;
    const int nn = min(64, N_NODES - node0);
    const int tid = threadIdx.x;
    if (tid < 64) cnt[tid] = 0;
    __syncthreads();
    const int gbeg = b * CAP;
    const int nE = gcnt[b];
    for (int i = tid; i < nE; i += 256)
        atomicAdd(&cnt[(staging[gbeg + i] >> 16) - node0], 1);
    __syncthreads();
    if (tid < 64) {
        int v = cnt[tid];
        int incl = v;
#pragma unroll
        for (int off = 1; off < 64; off <<= 1) {
            int t = __shfl_up(incl, off, 64);
            if (tid >= off) incl += t;
        }
        base[tid] = gbeg + incl - v;
        cur[tid] = 0;
        if (tid < nn) {
            offs[node0 + tid] = gbeg + incl - v;
            degs[node0 + tid] = v;
        }
    }
    __syncthreads();
    for (int i = tid; i < nE; i += 256) {
        unsigned int e = staging[gbeg + i];
        int dl = (int)(e >> 16) - node0;
        int pos = base[dl] + atomicAdd(&cur[dl], 1);
        gsrt[pos] = (ushort_t)(e & 0xFFFFu);
    }
}

// ---------- layer-1 node pass, TWO NODES PER WAVE, with FUSED layer-2 GEMM ----------
// Phase-B inner loop uses v_fma_mix_f32 (fused f16->f32 in the FMA) and byte-offset
// pre-scaling (shift once per edge in phase A, not per slot in phase B).
__global__ __launch_bounds__(256) void k_node1(
        const int* __restrict__ offs, const int* __restrict__ degs,
        const ushort_t* __restrict__ srt,
        const float* __restrict__ as_, const float* __restrict__ ad_,
        const __half* __restrict__ H, const float* __restrict__ bias,
        const float* __restrict__ W2, const float* __restrict__ a_src2,
        const float* __restrict__ a_dst2,
        __half* __restrict__ g2, float* __restrict__ as2, float* __restrict__ ad2) {
    constexpr int C = 64, G = 8, NR = 4;   // G lanes/row, NR rows per slot per node
    __shared__ float hrow[4][2][64];       // [wave-in-block][half][channel]
    const int wid = (int)(((long long)blockIdx.x * blockDim.x + threadIdx.x) >> 6);
    if (wid * 2 >= N_NODES) return;
    const int lane = threadIdx.x & 63;
    const int ln   = lane & 31;
    const int node = wid * 2 + (lane >> 5);
    const bool nv = node < N_NODES;
    const int beg = nv ? offs[node] : 0;
    const int deg = nv ? degs[node] : 0;
    const int mdeg = max(deg, __shfl_xor(deg, 32, 64));
    const float adn = nv ? ad_[node] : 0.f;
    const int g  = ln / G;
    const int cl = ln % G;
    const char* Hb = (const char*)H + cl * 16;   // per-lane channel base (bytes)
    float acc[8] = {};
    float ssum = 0.f;

    for (int base = 0; base < mdeg; base += 32) {
        const int nb  = min(32, deg - base);
        const int mnb = min(32, mdeg - base);
        // ---- phase A ----
        int sB = 0;
        float p = 0.f;
        if (ln < nb) {
            int s = srt[beg + base + ln];
            float e = as_[s] + adn;
            e = (e > 0.f) ? e : NEG_SLOPE * e;
            p = __expf(e - MB_SHIFT);
            sB = s << 7;                  // byte offset: s * C * sizeof(half) = s*128
        }
        ssum += p;
        // ---- phase B ----
        int j = 0;
        for (; j + NR < mnb; j += 2 * NR) {
            const int i0 = j + g, i1 = j + NR + g;
            const int   o0 = __shfl(sB, i0, 32);
            const int   o1 = __shfl(sB, i1, 32);
            const float p0 = __shfl(p, i0, 32);
            const float p1 = __shfl(p, i1, 32);
            const uint4 ra = *(const uint4*)(Hb + o0);
            const uint4 rb = *(const uint4*)(Hb + o1);
            fmix(acc[0], acc[1], ra.x, p0);
            fmix(acc[2], acc[3], ra.y, p0);
            fmix(acc[4], acc[5], ra.z, p0);
            fmix(acc[6], acc[7], ra.w, p0);
            fmix(acc[0], acc[1], rb.x, p1);
            fmix(acc[2], acc[3], rb.y, p1);
            fmix(acc[4], acc[5], rb.z, p1);
            fmix(acc[6], acc[7], rb.w, p1);
        }
        if (j < mnb) {
            const int i0 = j + g;
            const int   o0 = __shfl(sB, i0, 32);
            const float p0 = __shfl(p, i0, 32);
            const uint4 ra = *(const uint4*)(Hb + o0);
            fmix(acc[0], acc[1], ra.x, p0);
            fmix(acc[2], acc[3], ra.y, p0);
            fmix(acc[4], acc[5], ra.z, p0);
            fmix(acc[6], acc[7], ra.w, p0);
        }
    }
    // ssum within each half
#pragma unroll
    for (int off = 1; off < 32; off <<= 1)
        ssum += __shfl_xor(ssum, off, 64);
    const float inv = 1.f / (ssum + 1e-30f);

    // fold-reduce: 2 steps, lane ends owning channels ch, ch+1
    const int b0 = (ln >> 3) & 1, b1 = (ln >> 4) & 1;
    float s0 = b0 ? acc[0] : acc[4];
    float s1 = b0 ? acc[1] : acc[5];
    float s2 = b0 ? acc[2] : acc[6];
    float s3 = b0 ? acc[3] : acc[7];
    float r0 = __shfl_xor(s0, 8, 64);
    float r1 = __shfl_xor(s1, 8, 64);
    float r2 = __shfl_xor(s2, 8, 64);
    float r3 = __shfl_xor(s3, 8, 64);
    float a0 = (b0 ? acc[4] : acc[0]) + r0;
    float a1 = (b0 ? acc[5] : acc[1]) + r1;
    float a2 = (b0 ? acc[6] : acc[2]) + r2;
    float a3 = (b0 ? acc[7] : acc[3]) + r3;
    float t0 = b1 ? a0 : a2;
    float t1 = b1 ? a1 : a3;
    float q0 = __shfl_xor(t0, 16, 64);
    float q1 = __shfl_xor(t1, 16, 64);
    float c0v = (b1 ? a2 : a0) + q0;
    float c1v = (b1 ? a3 : a1) + q1;
    const int ch = cl * 8 + b0 * 4 + b1 * 2;

    // bias + ELU -> h2 row values
    float v0 = c0v * inv + bias[ch];
    float v1 = c1v * inv + bias[ch + 1];
    v0 = (v0 > 0.f) ? v0 : expm1f(v0);
    v1 = (v1 > 0.f) ? v1 : expm1f(v1);

    // ---- fused layer-2 GEMM ----
    const int w  = threadIdx.x >> 6;
    const int hf = lane >> 5;
    float2 hv2 = {v0, v1};
    *(float2*)&hrow[w][hf][ch] = hv2;    // intra-wave: ds_write then ds_read, in order

    float y = 0.f;
    const float* wp = W2 + ln;           // W2[ch][ln] = W2[ch*32+ln], coalesced per ch
#pragma unroll
    for (int cc = 0; cc < 64; cc += 4) {
        float4 hv = *(const float4*)&hrow[w][hf][cc];   // broadcast read
        y += hv.x * wp[(cc + 0) * 32] + hv.y * wp[(cc + 1) * 32]
           + hv.z * wp[(cc + 2) * 32] + hv.w * wp[(cc + 3) * 32];
    }
    // attention dots for layer 2
    float ts = y * a_src2[ln];
    float td = y * a_dst2[ln];
#pragma unroll
    for (int off = 1; off < 32; off <<= 1) {
        ts += __shfl_xor(ts, off, 64);
        td += __shfl_xor(td, off, 64);
    }
    if (nv) {
        g2[(long long)node * 32 + ln] = __float2half_rn(y);
        if (ln == 0) { as2[node] = ts; ad2[node] = td; }
    }
}

// ---------- layer-2 node pass: TWO NODES PER WAVE (C=32, ushort srt, fma_mix) ----------
template<int C, bool ELU>
__global__ __launch_bounds__(256) void k_node(
        const int* __restrict__ offs, const int* __restrict__ degs,
        const ushort_t* __restrict__ srt,
        const float* __restrict__ as_, const float* __restrict__ ad_,
        const __half* __restrict__ H, const float* __restrict__ bias,
        float* __restrict__ out) {
    constexpr int G  = C / 8;     // 4 for C=32
    constexpr int NR = 32 / G;    // 8
    const int wid = (int)(((long long)blockIdx.x * blockDim.x + threadIdx.x) >> 6);
    if (wid * 2 >= N_NODES) return;
    const int lane = threadIdx.x & 63;
    const int ln   = lane & 31;
    const int node = wid * 2 + (lane >> 5);
    const bool nv = node < N_NODES;
    const int beg = nv ? offs[node] : 0;
    const int deg = nv ? degs[node] : 0;
    const int mdeg = max(deg, __shfl_xor(deg, 32, 64));
    const float adn = nv ? ad_[node] : 0.f;
    const int g  = ln / G;
    const int cl = ln % G;
    const char* Hb = (const char*)H + cl * 16;
    float acc[8] = {};
    float ssum = 0.f;

    for (int base = 0; base < mdeg; base += 32) {
        const int nb  = min(32, deg - base);
        const int mnb = min(32, mdeg - base);
        int sB = 0;
        float p = 0.f;
        if (ln < nb) {
            int s = srt[beg + base + ln];
            float e = as_[s] + adn;
            e = (e > 0.f) ? e : NEG_SLOPE * e;
            p = __expf(e - MB_SHIFT);
            sB = s << 6;                  // byte offset: s * 32 * 2 = s*64
        }
        ssum += p;
        int j = 0;
        for (; j + NR < mnb; j += 2 * NR) {
            const int i0 = j + g, i1 = j + NR + g;
            const int   o0 = __shfl(sB, i0, 32);
            const int   o1 = __shfl(sB, i1, 32);
            const float p0 = __shfl(p, i0, 32);
            const float p1 = __shfl(p, i1, 32);
            const uint4 ra = *(const uint4*)(Hb + o0);
            const uint4 rb = *(const uint4*)(Hb + o1);
            fmix(acc[0], acc[1], ra.x, p0);
            fmix(acc[2], acc[3], ra.y, p0);
            fmix(acc[4], acc[5], ra.z, p0);
            fmix(acc[6], acc[7], ra.w, p0);
            fmix(acc[0], acc[1], rb.x, p1);
            fmix(acc[2], acc[3], rb.y, p1);
            fmix(acc[4], acc[5], rb.z, p1);
            fmix(acc[6], acc[7], rb.w, p1);
        }
        if (j < mnb) {
            const int i0 = j + g;
            const int   o0 = __shfl(sB, i0, 32);
            const float p0 = __shfl(p, i0, 32);
            const uint4 ra = *(const uint4*)(Hb + o0);
            fmix(acc[0], acc[1], ra.x, p0);
            fmix(acc[2], acc[3], ra.y, p0);
            fmix(acc[4], acc[5], ra.z, p0);
            fmix(acc[6], acc[7], ra.w, p0);
        }
    }
#pragma unroll
    for (int off = 1; off < 32; off <<= 1)
        ssum += __shfl_xor(ssum, off, 64);
    const float inv = 1.f / (ssum + 1e-30f);

    // C=32: 3 fold steps; lane owns 1 channel.
    const int b0 = (ln >> 2) & 1, b1 = (ln >> 3) & 1, b2 = (ln >> 4) & 1;
    float s0 = b0 ? acc[0] : acc[4];
    float s1 = b0 ? acc[1] : acc[5];
    float s2 = b0 ? acc[2] : acc[6];
    float s3 = b0 ? acc[3] : acc[7];
    float r0 = __shfl_xor(s0, 4, 64);
    float r1 = __shfl_xor(s1, 4, 64);
    float r2 = __shfl_xor(s2, 4, 64);
    float r3 = __shfl_xor(s3, 4, 64);
    float a0 = (b0 ? acc[4] : acc[0]) + r0;
    float a1 = (b0 ? acc[5] : acc[1]) + r1;
    float a2 = (b0 ? acc[6] : acc[2]) + r2;
    float a3 = (b0 ? acc[7] : acc[3]) + r3;
    float t0 = b1 ? a0 : a2;
    float t1 = b1 ? a1 : a3;
    float q0 = __shfl_xor(t0, 8, 64);
    float q1 = __shfl_xor(t1, 8, 64);
    float c0 = (b1 ? a2 : a0) + q0;
    float c1 = (b1 ? a3 : a1) + q1;
    float u = b2 ? c0 : c1;
    float ww = __shfl_xor(u, 16, 64);
    float v0 = (b2 ? c1 : c0) + ww;
    const int ch = cl * 8 + b0 * 4 + b1 * 2 + b2;
    if (nv) {
        float v = v0 * inv + bias[ch];
        if (ELU) v = (v > 0.f) ? v : expm1f(v);
        out[(long long)node * C + ch] = v;
    }
}

extern "C" void kernel_launch(void* const* d_in, const int* in_sizes, int n_in,
                              void* d_out, int out_size, void* d_ws, size_t ws_size,
                              hipStream_t stream) {
    const float* x      = (const float*)d_in[0];
    const void*  edges  = d_in[1];
    const float* W1     = (const float*)d_in[2];
    const float* a_src1 = (const float*)d_in[3];
    const float* a_dst1 = (const float*)d_in[4];
    const float* b1     = (const float*)d_in[5];
    const float* W2     = (const float*)d_in[6];
    const float* a_src2 = (const float*)d_in[7];
    const float* a_dst2 = (const float*)d_in[8];
    const float* b2     = (const float*)d_in[9];

    char* ws = (char*)d_ws;
    size_t off = 0;
    auto alloc = [&](size_t bytes) { char* p = ws + off; off += (bytes + 255) & ~size_t(255); return p; };
    __half*       h1      = (__half*)      alloc((size_t)N_NODES * 64 * 2);  // fp16 H, layer 1
    __half*       g2      = (__half*)      alloc((size_t)N_NODES * 32 * 2);  // fp16 h, layer 2
    float*        as1     = (float*)       alloc((size_t)N_NODES * 4);
    float*        ad1     = (float*)       alloc((size_t)N_NODES * 4);
    float*        as2     = (float*)       alloc((size_t)N_NODES * 4);
    float*        ad2     = (float*)       alloc((size_t)N_NODES * 4);
    int*          gcnt    = (int*)         alloc((size_t)NBUCK * 4);
    int*          offs    = (int*)         alloc((size_t)N_NODES * 4);
    int*          degs    = (int*)         alloc((size_t)N_NODES * 4);
    unsigned int* staging = (unsigned int*)alloc((size_t)NBUCK * CAP * 4);   // 6.4MB
    ushort_t*     gsrt    = (ushort_t*)    alloc((size_t)NBUCK * CAP * 2);   // 3.2MB
    float*        out     = (float*)d_out;

    const int NODE_BLOCKS = (((N_NODES + 1) / 2) * 64 + 255) / 256;  // 2 nodes/wave

    // 1) zero bucket cursors
    k_zero<<<(NBUCK + 255) / 256, 256, 0, stream>>>(gcnt);
    // 2) binscatter || layer-1 GEMM (independent; union'd LDS)
    k_scatgemm<<<NCHUNK + NGEMM1, 256, 0, stream>>>(
        edges, gcnt, staging, x, W1, a_src1, a_dst1, h1, as1, ad1);
    // 3) per-bucket sort -> ushort srt + offs/degs
    k_bsort<<<NBUCK, 256, 0, stream>>>(staging, gcnt, offs, degs, gsrt);
    // 4) layer-1 aggregation + ELU + FUSED layer-2 GEMM + att dots (2 nodes/wave)
    k_node1<<<NODE_BLOCKS, 256, 0, stream>>>(
        offs, degs, gsrt, as1, ad1, h1, b1, W2, a_src2, a_dst2, g2, as2, ad2);
    // 5) layer-2 aggregation -> final output
    k_node<32, false><<<NODE_BLOCKS, 256, 0, stream>>>(
        offs, degs, gsrt, as2, ad2, g2, b2, out);
}